// Round 4
// baseline (3983.592 us; speedup 1.0000x reference)
//
#include <hip/hip_runtime.h>

// Furthest Point Sampling, B=8, C=3, N=65536, NUM_POINTS=1024.
//
// R4 design: 16 blocks x 512 threads per batch (128 blocks total), coords of each
// block's 4096 points register-resident (8 pts/thread). Per iteration:
//   1. register distance update + per-thread argmax carrying the candidate's COORDS,
//   2. payload-carrying butterfly reduce (wave, then block via LDS),
//   3. block publishes a 32B record {key, x|tag, y|tag, z|tag} to its own slot
//      (4 relaxed agent-scope u64 stores; every word self-validates via tag = it
//      in its low 16 bits -- no ordering, no zeroing, no RMW),
//   4. all 64 lanes of wave 0 poll the 64-word region in ONE dwordx2 load round,
//      wait until all tags match, then a payload-carrying butterfly yields the
//      global winner's index AND coords -- no query-point global load at all.
// Slot regions are double-buffered by (it & 1): a block cannot get 2 iterations
// ahead (its it+1 poll needs every peer's it+1 publish), so no overwrite hazard.
//
// Key packing (idx < 65536 fits 16 bits): dist_bits(32) | (0xFFFF-idx)(16) | it(16).
// Within an iteration all tags equal -> max key = max dist, tie -> smaller index
// == jnp.argmax first-occurrence. dist >= 0 so float bits are monotone.
// Distance math: __fmul_rn/__fadd_rn (no FMA contraction) to bit-match numpy.

namespace {

constexpr int kB = 8;
constexpr int kN = 65536;
constexpr int kNP = 1024;
constexpr int kPB = 16;                      // blocks per batch
constexpr int kThreads = 512;
constexpr int kPPT = kN / (kPB * kThreads);  // 8 points per thread
constexpr int kGrp = kPPT / 4;               // 2 float4 groups
constexpr int kWaves = kThreads / 64;        // 8
constexpr int kSlotWords = 4;                // key, x|tag, y|tag, z|tag

__device__ __forceinline__ unsigned long long u64max(unsigned long long a,
                                                     unsigned long long b) {
  return a > b ? a : b;
}

__device__ __forceinline__ unsigned long long shfl_xor_u64(unsigned long long v, int off) {
  return (unsigned long long)__shfl_xor((long long)v, off, 64);
}

__global__ __launch_bounds__(kThreads) void fps_kernel(const float* __restrict__ pts,
                                                       float* __restrict__ out,
                                                       unsigned long long* __restrict__ slots) {
  const int batch = blockIdx.x & 7;
  const int slice = blockIdx.x >> 3;
  const int tid = threadIdx.x;
  const int lane = tid & 63;
  const int wave = tid >> 6;

  const float* __restrict__ xb = pts + (size_t)batch * 3 * kN;
  const float* __restrict__ yb = xb + kN;
  const float* __restrict__ zb = xb + 2 * kN;

  __shared__ unsigned long long s_wkey[kWaves];
  __shared__ float s_wx[kWaves], s_wy[kWaves], s_wz[kWaves];
  __shared__ int s_hist[kNP];
  __shared__ float s_q[3];

  // Register-resident coords: block owns [slice*4096, slice*4096+4096).
  const int sbase = slice * (kThreads * kPPT);
  float px[kPPT], py[kPPT], pz[kPPT], dist[kPPT];
#pragma unroll
  for (int g = 0; g < kGrp; ++g) {
    const int base = sbase + g * (kThreads * 4) + tid * 4;
    const float4 vx = *reinterpret_cast<const float4*>(xb + base);
    const float4 vy = *reinterpret_cast<const float4*>(yb + base);
    const float4 vz = *reinterpret_cast<const float4*>(zb + base);
    px[g * 4 + 0] = vx.x; px[g * 4 + 1] = vx.y; px[g * 4 + 2] = vx.z; px[g * 4 + 3] = vx.w;
    py[g * 4 + 0] = vy.x; py[g * 4 + 1] = vy.y; py[g * 4 + 2] = vy.z; py[g * 4 + 3] = vy.w;
    pz[g * 4 + 0] = vz.x; pz[g * 4 + 1] = vz.y; pz[g * 4 + 2] = vz.z; pz[g * 4 + 3] = vz.w;
  }
#pragma unroll
  for (int k = 0; k < kPPT; ++k) dist[k] = 1e10f;

  // Seed: index 0 (uniform broadcast load, once).
  float qx = xb[0], qy = yb[0], qz = zb[0];

  unsigned long long* const sb_batch = slots + (size_t)batch * 2 * kPB * kSlotWords;

  for (int it = 1; it < kNP; ++it) {
    const unsigned tag = (unsigned)it;  // < 1024, fits 16 bits; 0xAAAA poison never matches

    // --- update dists + per-thread argmax carrying candidate coords ---
    float bd = -1.0f, bx = 0.f, by = 0.f, bz = 0.f;
    int bi = 0;
#pragma unroll
    for (int g = 0; g < kGrp; ++g) {
#pragma unroll
      for (int j = 0; j < 4; ++j) {
        const int k = g * 4 + j;
        const float dx = px[k] - qx;
        const float dy = py[k] - qy;
        const float dz = pz[k] - qz;
        const float ss =
            __fadd_rn(__fadd_rn(__fmul_rn(dx, dx), __fmul_rn(dy, dy)), __fmul_rn(dz, dz));
        const float nd = fminf(dist[k], ss);
        dist[k] = nd;
        if (nd > bd) {  // strict '>' + ascending scan keeps earliest index
          bd = nd;
          bi = sbase + g * (kThreads * 4) + tid * 4 + j;
          bx = px[k]; by = py[k]; bz = pz[k];
        }
      }
    }

    // key: dist(32) | (0xFFFF - idx)(16) | tag(16)
    unsigned long long key = ((unsigned long long)__float_as_uint(bd) << 32) |
                             ((unsigned long long)(0xFFFFu - (unsigned)bi) << 16) |
                             (unsigned long long)tag;

    // --- wave butterfly, payload-carrying ---
#pragma unroll
    for (int off = 32; off > 0; off >>= 1) {
      const unsigned long long ok = shfl_xor_u64(key, off);
      const float ox = __shfl_xor(bx, off, 64);
      const float oy = __shfl_xor(by, off, 64);
      const float oz = __shfl_xor(bz, off, 64);
      if (ok > key) { key = ok; bx = ox; by = oy; bz = oz; }
    }
    if (lane == 0) {
      s_wkey[wave] = key;
      s_wx[wave] = bx; s_wy[wave] = by; s_wz[wave] = bz;
    }
    __syncthreads();

    if (wave == 0) {
      // --- block reduce over 8 wave results (payload-carrying) ---
      unsigned long long k = s_wkey[lane & (kWaves - 1)];
      float x = s_wx[lane & (kWaves - 1)];
      float y = s_wy[lane & (kWaves - 1)];
      float z = s_wz[lane & (kWaves - 1)];
#pragma unroll
      for (int off = 1; off < kWaves; off <<= 1) {
        const unsigned long long ok = shfl_xor_u64(k, off);
        const float ox = __shfl_xor(x, off, 64);
        const float oy = __shfl_xor(y, off, 64);
        const float oz = __shfl_xor(z, off, 64);
        if (ok > k) { k = ok; x = ox; y = oy; z = oz; }
      }

      // --- publish 32B record; every word tagged, no ordering needed ---
      unsigned long long* const rb = sb_batch + (size_t)(it & 1) * kPB * kSlotWords;
      if (lane == 0) {
        unsigned long long* const my = rb + slice * kSlotWords;
        __hip_atomic_store(my + 0, k, __ATOMIC_RELAXED, __HIP_MEMORY_SCOPE_AGENT);
        __hip_atomic_store(my + 1,
                           ((unsigned long long)__float_as_uint(x) << 32) | tag,
                           __ATOMIC_RELAXED, __HIP_MEMORY_SCOPE_AGENT);
        __hip_atomic_store(my + 2,
                           ((unsigned long long)__float_as_uint(y) << 32) | tag,
                           __ATOMIC_RELAXED, __HIP_MEMORY_SCOPE_AGENT);
        __hip_atomic_store(my + 3,
                           ((unsigned long long)__float_as_uint(z) << 32) | tag,
                           __ATOMIC_RELAXED, __HIP_MEMORY_SCOPE_AGENT);
      }

      // --- poll: 64 words == 64 lanes, one dwordx2 load round per attempt ---
      unsigned long long w;
      do {
        w = __hip_atomic_load(rb + lane, __ATOMIC_RELAXED, __HIP_MEMORY_SCOPE_AGENT);
      } while (!__all((unsigned)(w & 0xFFFFull) == tag));

      // Broadcast each slot's key to its 4 lanes, then butterfly across slots
      // carrying this lane's component word.
      unsigned long long gk = (unsigned long long)__shfl((long long)w, lane & ~3, 64);
#pragma unroll
      for (int off = 4; off < 64; off <<= 1) {
        const unsigned long long ogk = shfl_xor_u64(gk, off);
        const unsigned long long ow = shfl_xor_u64(w, off);
        if (ogk > gk) { gk = ogk; w = ow; }
      }
      // lanes 0..3 now hold the winner's {key, x|tag, y|tag, z|tag}
      if (lane == 0) s_hist[it] = (int)(0xFFFFu - ((unsigned)(gk >> 16) & 0xFFFFu));
      if (lane == 1) s_q[0] = __uint_as_float((unsigned)(w >> 32));
      if (lane == 2) s_q[1] = __uint_as_float((unsigned)(w >> 32));
      if (lane == 3) s_q[2] = __uint_as_float((unsigned)(w >> 32));
    }
    __syncthreads();

    qx = s_q[0];
    qy = s_q[1];
    qz = s_q[2];
  }

  // --- gather: out[b][c][j] = points[b][c][idx_j]; slice-0 block per batch ---
  if (slice == 0) {
    float* __restrict__ ob = out + (size_t)batch * 3 * kNP;
    for (int j = tid; j < kNP; j += kThreads) {
      const int id = (j == 0) ? 0 : s_hist[j];
      ob[j] = xb[id];
      ob[kNP + j] = yb[id];
      ob[2 * kNP + j] = zb[id];
    }
  }
}

}  // namespace

extern "C" void kernel_launch(void* const* d_in, const int* in_sizes, int n_in,
                              void* d_out, int out_size, void* d_ws, size_t ws_size,
                              hipStream_t stream) {
  (void)in_sizes;
  (void)n_in;
  (void)out_size;
  (void)ws_size;
  const float* pts = (const float*)d_in[0];
  float* out = (float*)d_out;
  // 8 batches x 2 parity regions x 16 slots x 4 u64 = 8 KB of d_ws.
  // Tag-validated (poison 0xAAAA never equals it<1024) -> NO memset needed.
  unsigned long long* slots = (unsigned long long*)d_ws;
  fps_kernel<<<dim3(kB * kPB), dim3(kThreads), 0, stream>>>(pts, out, slots);
}

// Round 5
// 2613.668 us; speedup vs baseline: 1.5241x; 1.5241x over previous
//
#include <hip/hip_runtime.h>

// Furthest Point Sampling, B=8, C=3, N=65536, NUM_POINTS=1024.
//
// R5 = R3 protocol (which timed tight at 1.78ms) + two critical-path cuts.
//   - 16 blocks x 512 threads per batch (128 blocks total); each block's 4096
//     points register-resident (8 pts/thread).
//   - Per iteration: register dist update + per-thread argmax -> wave butterfly ->
//     LDS (parity-double-buffered) -> ONE barrier -> every wave redundantly reduces
//     the 8 wave-candidates; wave 0 lane 0 publishes the block key (8B relaxed
//     agent store, own slot); ALL waves poll the batch's 16-slot/128B line and
//     compute the global winner locally (no second barrier, no LDS broadcast).
//   - Slot regions are FRESH per iteration (1 MB ws): each line is written exactly
//     once, ever -> no writer/poller line ping-pong (R4's regression). Validity is
//     a tag match (key low 16 bits == it), so no memset: 0xAA poison = 0xAAAA tag
//     never equals it < 1024.
//
// Key packing (idx < 65536): dist_bits(32) | (0xFFFF - idx)(16) | it(16).
// Same tag on all keys of an iteration -> max key = max dist, tie -> smaller
// index == jnp.argmax first-occurrence. dist >= 0 so float bits are monotone.
// Distance math: __fmul_rn/__fadd_rn (no FMA contraction) to bit-match numpy.
// Query-point coords re-loaded per wave from global (uniform; batch's 768 KB is
// XCD-L2-resident ~200cy -- cheaper than any publish-payload scheme, per R4).

namespace {

constexpr int kB = 8;
constexpr int kN = 65536;
constexpr int kNP = 1024;
constexpr int kPB = 16;                      // blocks per batch (16 slots = one 128B line)
constexpr int kThreads = 512;
constexpr int kPPT = kN / (kPB * kThreads);  // 8 points per thread
constexpr int kGrp = kPPT / 4;               // 2 float4 groups
constexpr int kWaves = kThreads / 64;        // 8

__device__ __forceinline__ unsigned long long shfl_xor_u64(unsigned long long v, int off) {
  return (unsigned long long)__shfl_xor((long long)v, off, 64);
}

__device__ __forceinline__ unsigned long long u64max(unsigned long long a,
                                                     unsigned long long b) {
  return a > b ? a : b;
}

__global__ __launch_bounds__(kThreads) void fps_kernel(const float* __restrict__ pts,
                                                       float* __restrict__ out,
                                                       unsigned long long* __restrict__ slots) {
  const int batch = blockIdx.x & 7;   // round-robin dispatch => batch pinned to one XCD
  const int slice = blockIdx.x >> 3;  // 0..15
  const int tid = threadIdx.x;
  const int lane = tid & 63;
  const int wave = tid >> 6;

  const float* __restrict__ xb = pts + (size_t)batch * 3 * kN;
  const float* __restrict__ yb = xb + kN;
  const float* __restrict__ zb = xb + 2 * kN;

  __shared__ unsigned long long s_wkey[2][kWaves];  // parity-double-buffered
  __shared__ int s_hist[kNP];

  // Register-resident coords: block owns [slice*4096, slice*4096+4096).
  const int sbase = slice * (kThreads * kPPT);
  float px[kPPT], py[kPPT], pz[kPPT], dist[kPPT];
#pragma unroll
  for (int g = 0; g < kGrp; ++g) {
    const int base = sbase + g * (kThreads * 4) + tid * 4;
    const float4 vx = *reinterpret_cast<const float4*>(xb + base);
    const float4 vy = *reinterpret_cast<const float4*>(yb + base);
    const float4 vz = *reinterpret_cast<const float4*>(zb + base);
    px[g * 4 + 0] = vx.x; px[g * 4 + 1] = vx.y; px[g * 4 + 2] = vx.z; px[g * 4 + 3] = vx.w;
    py[g * 4 + 0] = vy.x; py[g * 4 + 1] = vy.y; py[g * 4 + 2] = vy.z; py[g * 4 + 3] = vy.w;
    pz[g * 4 + 0] = vz.x; pz[g * 4 + 1] = vz.y; pz[g * 4 + 2] = vz.z; pz[g * 4 + 3] = vz.w;
  }
#pragma unroll
  for (int k = 0; k < kPPT; ++k) dist[k] = 1e10f;

  // Seed: index 0 (uniform broadcast load).
  float qx = xb[0], qy = yb[0], qz = zb[0];

  unsigned long long* const sb_batch = slots + (size_t)batch * kNP * kPB;

  for (int it = 1; it < kNP; ++it) {
    const int p = it & 1;

    // --- update dists + per-thread argmax (ascending index, strict '>') ---
    float bd = -1.0f;
    int bi = 0;
#pragma unroll
    for (int g = 0; g < kGrp; ++g) {
#pragma unroll
      for (int j = 0; j < 4; ++j) {
        const int k = g * 4 + j;
        const float dx = px[k] - qx;
        const float dy = py[k] - qy;
        const float dz = pz[k] - qz;
        const float ss =
            __fadd_rn(__fadd_rn(__fmul_rn(dx, dx), __fmul_rn(dy, dy)), __fmul_rn(dz, dz));
        const float nd = fminf(dist[k], ss);
        dist[k] = nd;
        if (nd > bd) {
          bd = nd;
          bi = sbase + g * (kThreads * 4) + tid * 4 + j;
        }
      }
    }

    // key: dist(32) | (0xFFFF - idx)(16) | it(16)  -- tag self-validates the slot.
    unsigned long long key = ((unsigned long long)__float_as_uint(bd) << 32) |
                             ((unsigned long long)(0xFFFFu - (unsigned)bi) << 16) |
                             (unsigned long long)(unsigned)it;

    // --- wave butterfly ---
#pragma unroll
    for (int off = 32; off > 0; off >>= 1) {
      key = u64max(key, shfl_xor_u64(key, off));
    }
    if (lane == 0) s_wkey[p][wave] = key;
    __syncthreads();  // the ONLY barrier in the iteration

    // --- every wave: block reduce (redundant), wave0 publishes ---
    unsigned long long bk = s_wkey[p][lane & (kWaves - 1)];
#pragma unroll
    for (int off = 1; off < kWaves; off <<= 1) {
      bk = u64max(bk, shfl_xor_u64(bk, off));
    }
    unsigned long long* const rb = sb_batch + (size_t)it * kPB;  // fresh 128B line
    if (wave == 0 && lane == 0) {
      __hip_atomic_store(rb + slice, bk, __ATOMIC_RELAXED, __HIP_MEMORY_SCOPE_AGENT);
    }

    // --- all waves poll the 16-slot line (64 lanes = 4x redundant) ---
    unsigned long long w;
    do {
      w = __hip_atomic_load(rb + (lane & (kPB - 1)), __ATOMIC_RELAXED,
                            __HIP_MEMORY_SCOPE_AGENT);
    } while (!__all((unsigned)(w & 0xFFFFull) == (unsigned)it));

    // Reduce 16 distinct slots (lanes hold slot lane&15): 4-step butterfly.
#pragma unroll
    for (int off = 1; off < kPB; off <<= 1) {
      w = u64max(w, shfl_xor_u64(w, off));
    }
    const int wi = (int)(0xFFFFu - ((unsigned)(w >> 16) & 0xFFFFu));
    if (wave == 0 && lane == 0) s_hist[it] = wi;

    // Uniform per-wave load of the winner's coords (XCD-L2 resident, ~200cy).
    qx = xb[wi];
    qy = yb[wi];
    qz = zb[wi];
  }

  __syncthreads();  // make s_hist visible for the gather

  // --- gather: out[b][c][j] = points[b][c][idx_j]; slice-0 block per batch ---
  if (slice == 0) {
    float* __restrict__ ob = out + (size_t)batch * 3 * kNP;
    for (int j = tid; j < kNP; j += kThreads) {
      const int id = (j == 0) ? 0 : s_hist[j];
      ob[j] = xb[id];
      ob[kNP + j] = yb[id];
      ob[2 * kNP + j] = zb[id];
    }
  }
}

}  // namespace

extern "C" void kernel_launch(void* const* d_in, const int* in_sizes, int n_in,
                              void* d_out, int out_size, void* d_ws, size_t ws_size,
                              hipStream_t stream) {
  (void)in_sizes;
  (void)n_in;
  (void)out_size;
  (void)ws_size;
  const float* pts = (const float*)d_in[0];
  float* out = (float*)d_out;
  // 8 batches x 1024 iters x 16 slots x 8B = 1 MB of d_ws. Tag-validated
  // (0xAA poison -> tag 0xAAAA never equals it < 1024) => NO memset needed,
  // and every slot line is written exactly once (no reuse ping-pong).
  unsigned long long* slots = (unsigned long long*)d_ws;
  fps_kernel<<<dim3(kB * kPB), dim3(kThreads), 0, stream>>>(pts, out, slots);
}

// Round 6
// 1768.027 us; speedup vs baseline: 2.2531x; 1.4783x over previous
//
#include <hip/hip_runtime.h>

// Furthest Point Sampling, B=8, C=3, N=65536, NUM_POINTS=1024.
//
// R6: R3's proven slot protocol + XCD-local L2 fast path for the cross-block
// argmax exchange, single poller wave, LDS mailbox, one barrier per iteration.
//
//  - 16 blocks x 256 threads per batch (128 blocks total). blockIdx%8 = batch,
//    so a batch's 16 blocks land on one XCD under the observed round-robin
//    dispatch (performance heuristic ONLY -- see fallback below).
//  - Each block's 4096 points register-resident (16 pts/thread).
//  - Per iteration: register dist update + argmax -> wave butterfly -> LDS ->
//    ONE __syncthreads -> wave 0: 4-key block reduce, publish block key to
//      line A (plain sc0 store -> lands in this XCD's shared L2, ~200cy RTT)
//      line B (agent-scope atomic store -> IC, the always-correct path)
//    then spin on line A with inline-asm sc0 loads (bypass L1, hit L2);
//    after 4 rounds, alternate rounds also merge agent-scope reads of line B,
//    so progress NEVER depends on XCD co-location -- only speed does.
//  - Winner index fans out to waves 1..3 via a tagged parity-double-buffered
//    LDS mailbox (they touch no global memory). Winner coords re-loaded
//    per-wave via readfirstlane'd scalar loads (points are XCD-L2 resident).
//  - Slot regions: 32 u64 words per (batch, it mod 16): words[0:16]=line A,
//    words[16:32]=line B. Tag (low 16 bits == it) validates; 0xAA poison =
//    0xAAAA never matches it<1024, so NO memset. Max block skew < 2 iters
//    (poll of it gates on all publishes of it), so reuse depth 16 is safe and
//    each line is quiescent when rewritten (no R4-style writer/poller ping-pong).
//
// Key packing (idx < 65536): dist_bits(32) | (0xFFFF - idx)(16) | it(16).
// Max key = max dist, tie -> smaller index == jnp.argmax first-occurrence
// (dist >= 0 so float bits are monotone; same tag on all keys of an iteration).
// Distance math: __fmul_rn/__fadd_rn (no FMA contraction) to bit-match numpy.

namespace {

constexpr int kB = 8;
constexpr int kN = 65536;
constexpr int kNP = 1024;
constexpr int kPB = 16;                      // blocks per batch (16 slots = one 128B line)
constexpr int kThreads = 256;
constexpr int kPPT = kN / (kPB * kThreads);  // 16 points per thread
constexpr int kGrp = kPPT / 4;               // 4 float4 groups
constexpr int kWaves = kThreads / 64;        // 4
constexpr int kRgn = 16;                     // slot-region reuse depth (skew < 2)

__device__ __forceinline__ unsigned long long shfl_xor_u64(unsigned long long v, int off) {
  return (unsigned long long)__shfl_xor((long long)v, off, 64);
}

__device__ __forceinline__ unsigned long long u64max(unsigned long long a,
                                                     unsigned long long b) {
  return a > b ? a : b;
}

// sc0 load: bypass L1, served by this XCD's L2 (the intra-XCD coherence point).
__device__ __forceinline__ unsigned long long load_l2(const unsigned long long* p) {
  unsigned long long v;
  asm volatile("global_load_dwordx2 %0, %1, off sc0\n\ts_waitcnt vmcnt(0)"
               : "=v"(v)
               : "v"(p)
               : "memory");
  return v;
}

// sc0 store: write-through to this XCD's L2 (no agent/IC round trip).
__device__ __forceinline__ void store_l2(unsigned long long* p, unsigned long long v) {
  asm volatile("global_store_dwordx2 %0, %1, off sc0" ::"v"(p), "v"(v) : "memory");
}

__global__ __launch_bounds__(kThreads) void fps_kernel(const float* __restrict__ pts,
                                                       float* __restrict__ out,
                                                       unsigned long long* __restrict__ slots) {
  const int batch = blockIdx.x & 7;   // round-robin dispatch => batch pinned to one XCD
  const int slice = blockIdx.x >> 3;  // 0..15
  const int tid = threadIdx.x;
  const int lane = tid & 63;
  const int wave = tid >> 6;

  const float* __restrict__ xb = pts + (size_t)batch * 3 * kN;
  const float* __restrict__ yb = xb + kN;
  const float* __restrict__ zb = xb + 2 * kN;

  __shared__ unsigned long long s_wkey[kWaves];
  __shared__ unsigned s_win[2];  // parity-double-buffered mailbox: (wi<<16)|it
  __shared__ int s_hist[kNP];

  if (tid == 0) {
    s_win[0] = 0xFFFFFFFFu;  // tag 0xFFFF never matches it < 1024
    s_win[1] = 0xFFFFFFFFu;
  }

  // Register-resident coords: block owns [slice*4096, slice*4096+4096).
  const int sbase = slice * (kThreads * kPPT);
  const int base0 = sbase + tid * 4;
  float px[kPPT], py[kPPT], pz[kPPT], dist[kPPT];
#pragma unroll
  for (int g = 0; g < kGrp; ++g) {
    const int base = base0 + g * (kThreads * 4);
    const float4 vx = *reinterpret_cast<const float4*>(xb + base);
    const float4 vy = *reinterpret_cast<const float4*>(yb + base);
    const float4 vz = *reinterpret_cast<const float4*>(zb + base);
    px[g * 4 + 0] = vx.x; px[g * 4 + 1] = vx.y; px[g * 4 + 2] = vx.z; px[g * 4 + 3] = vx.w;
    py[g * 4 + 0] = vy.x; py[g * 4 + 1] = vy.y; py[g * 4 + 2] = vy.z; py[g * 4 + 3] = vy.w;
    pz[g * 4 + 0] = vz.x; pz[g * 4 + 1] = vz.y; pz[g * 4 + 2] = vz.z; pz[g * 4 + 3] = vz.w;
  }
#pragma unroll
  for (int k = 0; k < kPPT; ++k) dist[k] = 1e10f;

  // Seed: index 0 (uniform broadcast load).
  float qx = xb[0], qy = yb[0], qz = zb[0];

  unsigned long long* const sb = slots + (size_t)batch * kRgn * 32;

  for (int it = 1; it < kNP; ++it) {
    // --- update dists + per-thread argmax (ascending index, strict '>') ---
    float bd = -1.0f;
    int bi = 0;
#pragma unroll
    for (int g = 0; g < kGrp; ++g) {
#pragma unroll
      for (int j = 0; j < 4; ++j) {
        const int k = g * 4 + j;
        const float dx = px[k] - qx;
        const float dy = py[k] - qy;
        const float dz = pz[k] - qz;
        const float ss =
            __fadd_rn(__fadd_rn(__fmul_rn(dx, dx), __fmul_rn(dy, dy)), __fmul_rn(dz, dz));
        const float nd = fminf(dist[k], ss);
        dist[k] = nd;
        if (nd > bd) {
          bd = nd;
          bi = base0 + g * (kThreads * 4) + j;
        }
      }
    }

    // key: dist(32) | (0xFFFF - idx)(16) | it(16)  -- tag self-validates slots.
    unsigned long long key = ((unsigned long long)__float_as_uint(bd) << 32) |
                             ((unsigned long long)(0xFFFFu - (unsigned)bi) << 16) |
                             (unsigned long long)(unsigned)it;

    // --- wave butterfly ---
#pragma unroll
    for (int off = 32; off > 0; off >>= 1) {
      key = u64max(key, shfl_xor_u64(key, off));
    }
    if (lane == 0) s_wkey[wave] = key;
    __syncthreads();  // the only barrier in the iteration

    int wi;
    if (wave == 0) {
      // --- block reduce over 4 wave keys ---
      unsigned long long bk = s_wkey[lane & (kWaves - 1)];
#pragma unroll
      for (int off = 1; off < kWaves; off <<= 1) {
        bk = u64max(bk, shfl_xor_u64(bk, off));
      }

      unsigned long long* const rgn = sb + (size_t)(it & (kRgn - 1)) * 32;
      if (lane == 0) {
        store_l2(rgn + slice, bk);  // fast path: XCD-local L2
        __hip_atomic_store(rgn + 16 + slice, bk, __ATOMIC_RELAXED,
                           __HIP_MEMORY_SCOPE_AGENT);  // correctness path: IC
      }

      // --- poll: L2 line fast rounds; merge IC line for guaranteed progress ---
      unsigned long long w;
      int round = 0;
      for (;;) {
        unsigned long long a = load_l2(rgn + (lane & (kPB - 1)));
        bool ok = (unsigned)(a & 0xFFFFull) == (unsigned)it;
        if (round > 4 && (round & 1)) {
          const unsigned long long fb = __hip_atomic_load(
              rgn + 16 + (lane & (kPB - 1)), __ATOMIC_RELAXED, __HIP_MEMORY_SCOPE_AGENT);
          if (!ok && (unsigned)(fb & 0xFFFFull) == (unsigned)it) {
            a = fb;
            ok = true;
          }
        }
        if (__all(ok)) {
          w = a;
          break;
        }
        ++round;
      }
      // Reduce 16 slots (lanes hold slot lane&15): 4-step butterfly.
#pragma unroll
      for (int off = 1; off < kPB; off <<= 1) {
        w = u64max(w, shfl_xor_u64(w, off));
      }
      wi = (int)(0xFFFFu - ((unsigned)(w >> 16) & 0xFFFFu));
      if (lane == 0) {
        s_hist[it] = wi;
        __hip_atomic_store(&s_win[it & 1], ((unsigned)wi << 16) | (unsigned)it,
                           __ATOMIC_RELAXED, __HIP_MEMORY_SCOPE_WORKGROUP);
      }
    } else {
      // --- non-leader waves: spin on the LDS mailbox (no global traffic) ---
      unsigned v;
      do {
        v = __hip_atomic_load(&s_win[it & 1], __ATOMIC_RELAXED, __HIP_MEMORY_SCOPE_WORKGROUP);
      } while ((v & 0xFFFFu) != (unsigned)it);
      wi = (int)(v >> 16);
    }

    // Winner coords: uniform scalar loads (points are XCD-L2 resident).
    const int wiu = __builtin_amdgcn_readfirstlane(wi);
    qx = xb[wiu];
    qy = yb[wiu];
    qz = zb[wiu];
  }

  __syncthreads();  // make s_hist fully visible for the gather

  // --- gather: out[b][c][j] = points[b][c][idx_j]; slice-0 block per batch ---
  if (slice == 0) {
    float* __restrict__ ob = out + (size_t)batch * 3 * kNP;
    for (int j = tid; j < kNP; j += kThreads) {
      const int id = (j == 0) ? 0 : s_hist[j];
      ob[j] = xb[id];
      ob[kNP + j] = yb[id];
      ob[2 * kNP + j] = zb[id];
    }
  }
}

}  // namespace

extern "C" void kernel_launch(void* const* d_in, const int* in_sizes, int n_in,
                              void* d_out, int out_size, void* d_ws, size_t ws_size,
                              hipStream_t stream) {
  (void)in_sizes;
  (void)n_in;
  (void)out_size;
  (void)ws_size;
  const float* pts = (const float*)d_in[0];
  float* out = (float*)d_out;
  // 8 batches x 16 regions x 32 u64 = 32 KB of d_ws. Tag-validated (0xAA poison
  // -> tag 0xAAAA never equals it < 1024) => no memset; reuse depth 16 >> max
  // block skew (<2 iterations), so regions are quiescent when rewritten.
  unsigned long long* slots = (unsigned long long*)d_ws;
  fps_kernel<<<dim3(kB * kPB), dim3(kThreads), 0, stream>>>(pts, out, slots);
}